// Round 1
// baseline (139.097 us; speedup 1.0000x reference)
//
#include <hip/hip_runtime.h>

// IMM loss: G=8192 groups of M=16 particles, D=64 dims each.
// terms = Lap(x,x) + Lap(y,y) - 2*Lap(x,y), Lap uses exp(-ws[j]*max(||a-b||,EPS)/D).
// Strategy: 1 wave = 4 groups (lane = gg*16 + j). Each lane holds its x/y rows in
// registers; partner rows fetched by __shfl rotation (offset o). xx/yy symmetric:
// only o=1..8 computed (o=8 weight 0.5, diagonal analytic). xy needs all o=0..15.

#define EPS_D 0.006f
#define DIMS 64

__global__ __launch_bounds__(256, 2)
void imm_loss_kernel(const float* __restrict__ ys_t,
                     const float* __restrict__ ys_r,
                     const float* __restrict__ w_scale,
                     const float* __restrict__ time_w,
                     float* __restrict__ partials)
{
    const int tid  = threadIdx.x;
    const int lane = tid & 63;
    const int wave = tid >> 6;
    const int j    = lane & 15;                       // particle index in group
    const int b    = (blockIdx.x * 4 + wave) * 64 + lane;  // global batch row = g*16 + j

    // Load this lane's x and y rows (256 B each) into registers.
    float x[DIMS], y[DIMS];
    const float4* xp = reinterpret_cast<const float4*>(ys_t + (size_t)b * DIMS);
    const float4* yp = reinterpret_cast<const float4*>(ys_r + (size_t)b * DIMS);
    #pragma unroll
    for (int c = 0; c < DIMS / 4; ++c) {
        float4 v = xp[c];
        x[4*c+0] = v.x; x[4*c+1] = v.y; x[4*c+2] = v.z; x[4*c+3] = v.w;
    }
    #pragma unroll
    for (int c = 0; c < DIMS / 4; ++c) {
        float4 v = yp[c];
        y[4*c+0] = v.x; y[4*c+1] = v.y; y[4*c+2] = v.z; y[4*c+3] = v.w;
    }

    const float s_j = w_scale[b] * (1.0f / (float)DIMS);   // ws[j]/D
    const float tw  = time_w[b & ~15];                     // time_weights[g*16]

    // xx and yy diagonals: d=0 -> clamped to EPS.
    float acc = 2.0f * __expf(-s_j * EPS_D);

    // o = 0: xy pair (j, j) — partner is local, no shuffle.
    {
        float d2 = 0.f;
        #pragma unroll
        for (int d = 0; d < DIMS; ++d) {
            float t = x[d] - y[d];
            d2 = fmaf(t, t, d2);
        }
        float dd = fmaxf(sqrtf(d2), EPS_D);
        acc -= 2.0f * __expf(-s_j * dd);
    }

    const int clbase = lane & 48;   // 16-lane cluster base (group within wave)

    // o = 1..8: xx, yy (each unordered pair once; o=8 hit twice -> weight 0.5) + xy.
    for (int o = 1; o <= 8; ++o) {
        const int src = clbase | ((j + o) & 15);
        const float s_k = __shfl(s_j, src, 64);
        float dxx = 0.f, dyy = 0.f, dxy = 0.f;
        #pragma unroll
        for (int d = 0; d < DIMS; ++d) {
            float xr = __shfl(x[d], src, 64);
            float yr = __shfl(y[d], src, 64);
            float tx = x[d] - xr;  dxx = fmaf(tx, tx, dxx);
            float ty = y[d] - yr;  dyy = fmaf(ty, ty, dyy);
            float tz = x[d] - yr;  dxy = fmaf(tz, tz, dxy);
        }
        const float w   = (o == 8) ? 0.5f : 1.0f;
        const float ddx = fmaxf(sqrtf(dxx), EPS_D);
        const float ddy = fmaxf(sqrtf(dyy), EPS_D);
        const float ddz = fmaxf(sqrtf(dxy), EPS_D);
        // symmetric contributions: ordered (j,k) uses s_j, ordered (k,j) uses s_k
        acc += w * (__expf(-s_j * ddx) + __expf(-s_k * ddx));
        acc += w * (__expf(-s_j * ddy) + __expf(-s_k * ddy));
        acc -= 2.0f * __expf(-s_j * ddz);
    }

    // o = 9..15: xy only (remaining ordered pairs).
    for (int o = 9; o <= 15; ++o) {
        const int src = clbase | ((j + o) & 15);
        float dxy = 0.f;
        #pragma unroll
        for (int d = 0; d < DIMS; ++d) {
            float yr = __shfl(y[d], src, 64);
            float tz = x[d] - yr;
            dxy = fmaf(tz, tz, dxy);
        }
        const float ddz = fmaxf(sqrtf(dxy), EPS_D);
        acc -= 2.0f * __expf(-s_j * ddz);
    }

    // Weight by tw (uniform per 16-lane cluster); reduce the whole wave
    // (sums 4 groups, each already tw-weighted).
    float val = acc * tw;
    #pragma unroll
    for (int off = 32; off; off >>= 1)
        val += __shfl_xor(val, off, 64);

    __shared__ float smem[4];
    if (lane == 0) smem[wave] = val;
    __syncthreads();
    if (tid == 0)
        partials[blockIdx.x] = smem[0] + smem[1] + smem[2] + smem[3];
}

__global__ void imm_reduce_kernel(const float* __restrict__ part, int n,
                                  float inv_scale, float* __restrict__ out)
{
    const int tid = threadIdx.x;
    float v = 0.f;
    for (int i = tid; i < n; i += 256) v += part[i];
    #pragma unroll
    for (int off = 32; off; off >>= 1) v += __shfl_xor(v, off, 64);
    __shared__ float s[4];
    if ((tid & 63) == 0) s[tid >> 6] = v;
    __syncthreads();
    if (tid == 0) out[0] = (s[0] + s[1] + s[2] + s[3]) * inv_scale;
}

extern "C" void kernel_launch(void* const* d_in, const int* in_sizes, int n_in,
                              void* d_out, int out_size, void* d_ws, size_t ws_size,
                              hipStream_t stream)
{
    const float* ys_t = (const float*)d_in[0];
    const float* ys_r = (const float*)d_in[1];
    const float* wsc  = (const float*)d_in[2];
    const float* twp  = (const float*)d_in[3];
    float* out      = (float*)d_out;
    float* partials = (float*)d_ws;

    const int B = in_sizes[2];      // 131072 (w_scale element count)
    const int G = B / 16;           // 8192 groups
    const int blocks = G / 16;      // 16 groups per block (4 waves x 4 groups)

    imm_loss_kernel<<<blocks, 256, 0, stream>>>(ys_t, ys_r, wsc, twp, partials);

    const float inv_scale = 1.0f / (256.0f * (float)G);  // 1/(M*M*G)
    imm_reduce_kernel<<<1, 256, 0, stream>>>(partials, blocks, inv_scale, out);
}

// Round 2
// 118.347 us; speedup vs baseline: 1.1753x; 1.1753x over previous
//
#include <hip/hip_runtime.h>

// IMM loss: G=8192 groups of M=16 particles, D=64 dims each, fp32.
// terms = Lap(x,x) + Lap(y,y) - 2*Lap(x,y), Lap = exp(-ws[j]*max(||a-b||,EPS)/D).
//
// R2: replace ds_bpermute shuffles with DPP row_ror:N (16-lane row rotation ==
// within-group partner permutation; groups are aligned 16-lane clusters).
// All offsets macro-expanded with compile-time DPP ctrl -> constant array
// indices -> x[]/y[] live fully in VGPRs (R1's VGPR=84 showed they didn't).
// Cross-lane moves now ride the VALU pipe (no lgkmcnt waits).

#define EPS_D 0.006f
#define DIMS 64

// Rotate within each 16-lane row by O (O = 1..15, compile-time constant).
#define ROT(v, O) __int_as_float(__builtin_amdgcn_update_dpp(              \
        0, __float_as_int(v), 0x120 + (O), 0xF, 0xF, false))

__global__ __launch_bounds__(256, 2)
void imm_loss_kernel(const float* __restrict__ ys_t,
                     const float* __restrict__ ys_r,
                     const float* __restrict__ w_scale,
                     const float* __restrict__ time_w,
                     float* __restrict__ partials)
{
    const int tid  = threadIdx.x;
    const int lane = tid & 63;
    const int wave = tid >> 6;
    const int b    = (blockIdx.x * 4 + wave) * 64 + lane;  // global row = g*16 + j

    // This lane's x and y rows (256 B each) -> registers.
    float x[DIMS], y[DIMS];
    const float4* xp = reinterpret_cast<const float4*>(ys_t + (size_t)b * DIMS);
    const float4* yp = reinterpret_cast<const float4*>(ys_r + (size_t)b * DIMS);
    #pragma unroll
    for (int c = 0; c < DIMS / 4; ++c) {
        float4 v = xp[c];
        x[4*c+0] = v.x; x[4*c+1] = v.y; x[4*c+2] = v.z; x[4*c+3] = v.w;
    }
    #pragma unroll
    for (int c = 0; c < DIMS / 4; ++c) {
        float4 v = yp[c];
        y[4*c+0] = v.x; y[4*c+1] = v.y; y[4*c+2] = v.z; y[4*c+3] = v.w;
    }

    const float s_j = w_scale[b] * (1.0f / (float)DIMS);   // ws[j]/D
    const float tw  = time_w[b & ~15];                     // time_weights[g*16]

    // xx and yy diagonals: d=0 clamps to EPS.
    float acc = 2.0f * __expf(-s_j * EPS_D);

    // offset 0: xy pair (j, j) — local, no rotation.
    {
        float d2 = 0.f;
        #pragma unroll
        for (int d = 0; d < DIMS; ++d) {
            float t = x[d] - y[d];
            d2 = fmaf(t, t, d2);
        }
        float dd = fmaxf(sqrtf(d2), EPS_D);
        acc -= 2.0f * __expf(-s_j * dd);
    }

    // Offsets 1..8: xx & yy via symmetry (both ordered directions from one
    // distance; offset 8 hit from both endpoints -> weight 0.5) + xy.
    // Offsets 9..15: remaining ordered xy pairs.
    // Note (xr - x)^2 == (x - xr)^2, so DPP result can be either sub operand.
#define FULL_O(O, W) {                                                     \
        const float s_k = ROT(s_j, O);                                     \
        float dxx = 0.f, dyy = 0.f, dxy = 0.f;                             \
        _Pragma("unroll")                                                  \
        for (int d = 0; d < DIMS; ++d) {                                   \
            float xr = ROT(x[d], O);                                       \
            float yr = ROT(y[d], O);                                       \
            float tx = xr - x[d];  dxx = fmaf(tx, tx, dxx);                \
            float ty = yr - y[d];  dyy = fmaf(ty, ty, dyy);                \
            float tz = yr - x[d];  dxy = fmaf(tz, tz, dxy);                \
        }                                                                  \
        const float ddx = fmaxf(sqrtf(dxx), EPS_D);                        \
        const float ddy = fmaxf(sqrtf(dyy), EPS_D);                        \
        const float ddz = fmaxf(sqrtf(dxy), EPS_D);                        \
        acc += (W) * (__expf(-s_j * ddx) + __expf(-s_k * ddx));            \
        acc += (W) * (__expf(-s_j * ddy) + __expf(-s_k * ddy));            \
        acc -= 2.0f * __expf(-s_j * ddz);                                  \
    }

#define XY_O(O) {                                                          \
        float dxy = 0.f;                                                   \
        _Pragma("unroll")                                                  \
        for (int d = 0; d < DIMS; ++d) {                                   \
            float tz = ROT(y[d], O) - x[d];                                \
            dxy = fmaf(tz, tz, dxy);                                       \
        }                                                                  \
        const float ddz = fmaxf(sqrtf(dxy), EPS_D);                        \
        acc -= 2.0f * __expf(-s_j * ddz);                                  \
    }

    FULL_O(1, 1.0f)
    FULL_O(2, 1.0f)
    FULL_O(3, 1.0f)
    FULL_O(4, 1.0f)
    FULL_O(5, 1.0f)
    FULL_O(6, 1.0f)
    FULL_O(7, 1.0f)
    FULL_O(8, 0.5f)
    XY_O(9)
    XY_O(10)
    XY_O(11)
    XY_O(12)
    XY_O(13)
    XY_O(14)
    XY_O(15)

    // tw is uniform per 16-lane cluster; wave reduction sums 4 groups.
    float val = acc * tw;
    #pragma unroll
    for (int off = 32; off; off >>= 1)
        val += __shfl_xor(val, off, 64);

    __shared__ float smem[4];
    if (lane == 0) smem[wave] = val;
    __syncthreads();
    if (tid == 0)
        partials[blockIdx.x] = smem[0] + smem[1] + smem[2] + smem[3];
}

__global__ void imm_reduce_kernel(const float* __restrict__ part, int n,
                                  float inv_scale, float* __restrict__ out)
{
    const int tid = threadIdx.x;
    float v = 0.f;
    for (int i = tid; i < n; i += 256) v += part[i];
    #pragma unroll
    for (int off = 32; off; off >>= 1) v += __shfl_xor(v, off, 64);
    __shared__ float s[4];
    if ((tid & 63) == 0) s[tid >> 6] = v;
    __syncthreads();
    if (tid == 0) out[0] = (s[0] + s[1] + s[2] + s[3]) * inv_scale;
}

extern "C" void kernel_launch(void* const* d_in, const int* in_sizes, int n_in,
                              void* d_out, int out_size, void* d_ws, size_t ws_size,
                              hipStream_t stream)
{
    const float* ys_t = (const float*)d_in[0];
    const float* ys_r = (const float*)d_in[1];
    const float* wsc  = (const float*)d_in[2];
    const float* twp  = (const float*)d_in[3];
    float* out      = (float*)d_out;
    float* partials = (float*)d_ws;

    const int B = in_sizes[2];      // 131072 (w_scale element count)
    const int G = B / 16;           // 8192 groups
    const int blocks = G / 16;      // 16 groups per block (4 waves x 4 groups)

    imm_loss_kernel<<<blocks, 256, 0, stream>>>(ys_t, ys_r, wsc, twp, partials);

    const float inv_scale = 1.0f / (256.0f * (float)G);  // 1/(M*M*G)
    imm_reduce_kernel<<<1, 256, 0, stream>>>(partials, blocks, inv_scale, out);
}